// Round 10
// baseline (234.243 us; speedup 1.0000x reference)
//
#include <hip/hip_runtime.h>

typedef _Float16 h8 __attribute__((ext_vector_type(8)));
typedef _Float16 h4 __attribute__((ext_vector_type(4)));
typedef _Float16 h2 __attribute__((ext_vector_type(2)));

// Problem constants (reference: B,M,N,L,S,KERN = 4,256,256,24,22,256; KERN==M → tile is identity)
constexpr int B_ = 4, M_ = 256, N_ = 256, L_ = 24, S_ = 22;
constexpr int SP_  = 24;    // shots padded to 24 (2 zero rows) for clean s-quads
constexpr int AP_  = 257;   // A4 [s][n] row pitch in h4 units (odd -> b64 reads 2-way, free)
constexpr int XTP_ = 25;    // XT [n][l] row pitch in h4 cells (200B rows, 50-dword stride, 2-way free)
constexpr int NYR_ = 280;   // Y rows per (bp,sq) plane (279 used)

// LDS layout (bytes):
constexpr int A4_BYTES = SP_ * AP_ * 8;            // 49,344  A[s][n] h4 over c
constexpr int XT_BYTES = N_ * XTP_ * 8;            // 51,200  x[n][l] h4 over b
constexpr int Y_BYTES  = 2 * 6 * NYR_ * 16;        // 53,760  Y[bp][sq][n'] 16B cells (2 h4: b-even, b-odd)
constexpr int XT_OFF   = A4_BYTES;                 // 49,344
constexpr int Y_OFF    = A4_BYTES + XT_BYTES;      // 100,544 (16B-aligned)
constexpr int WMAX_OFF = Y_OFF + Y_BYTES;          // 154,304
constexpr int LDS_BYTES = WMAX_OFF + 64;           // 154,368 (16 wave maxes) <= 163,840
constexpr int XT_OFF_H4 = XT_OFF / 8;              // 6,168
constexpr int XT_OFF_H2 = XT_OFF / 4;              // 12,336 (h2 view)
constexpr int Y_OFF_H4  = Y_OFF / 8;               // 12,568
constexpr int Y_OFF_H8  = Y_OFF / 16;              // 6,284

// Color bases as COMPILE-TIME constants (validated R6/R8/R9/R10):
constexpr float FR[L_] = {  // mu = 620
    6.252150e-05f, 1.904358e-04f, 5.418690e-04f, 1.440515e-03f, 3.577400e-03f,
    8.299750e-03f, 1.798893e-02f, 3.642490e-02f, 6.890060e-02f, 1.217600e-01f,
    2.010120e-01f, 3.100190e-01f, 4.466857e-01f, 6.012587e-01f, 7.560710e-01f,
    8.881955e-01f, 9.747661e-01f, 9.993953e-01f, 9.572367e-01f, 8.565352e-01f,
    7.160078e-01f, 5.591580e-01f, 4.079402e-01f, 2.780373e-01f};
constexpr float FG[L_] = {  // mu = 550
    1.110900e-02f, 2.348440e-02f, 4.638000e-02f, 8.557090e-02f, 1.474900e-01f,
    2.374920e-01f, 3.572560e-01f, 5.020580e-01f, 6.591400e-01f, 8.084270e-01f,
    9.262975e-01f, 9.915296e-01f, 9.915296e-01f, 9.262975e-01f, 8.084270e-01f,
    6.591400e-01f, 5.020580e-01f, 3.572560e-01f, 2.374920e-01f, 1.474900e-01f,
    8.557090e-02f, 4.638000e-02f, 2.348440e-02f, 1.110900e-02f};
constexpr float FB[L_] = {  // mu = 450 (pairs with wb)
    6.065307e-01f, 7.609727e-01f, 8.919300e-01f, 9.766475e-01f, 9.990553e-01f,
    9.547420e-01f, 8.523698e-01f, 7.109096e-01f, 5.539184e-01f, 4.032022e-01f,
    2.741855e-01f, 1.741852e-01f, 1.033776e-01f, 5.731640e-02f, 2.968800e-02f,
    1.436580e-02f, 6.494090e-03f, 2.742560e-03f, 1.079230e-03f, 3.988070e-04f,
    1.369660e-04f, 4.417250e-05f, 1.327420e-05f, 3.726650e-06f};
constexpr float FC[L_] = {  // mu = 500 (pairs with wc)
    1.353353e-01f, 2.204053e-01f, 3.353338e-01f, 4.766271e-01f, 6.328849e-01f,
    7.850828e-01f, 9.098110e-01f, 9.849909e-01f, 9.962264e-01f, 9.413024e-01f,
    8.308921e-01f, 6.851808e-01f, 5.278508e-01f, 3.798934e-01f, 2.554222e-01f,
    1.604349e-01f, 9.414200e-02f, 5.160780e-02f, 2.642960e-02f, 1.264440e-02f,
    5.651680e-03f, 2.359870e-03f, 9.205430e-04f, 3.354630e-04f};

__device__ __forceinline__ float fdot2(h2 a, h2 b, float c) {
    return __builtin_amdgcn_fdot2(a, b, c, false);
}

// Phase B l-half (verified correct R14/R19). With the 1024-thread 4-way
// split each thread runs exactly ONE instance: acc 24 regs + <=12 in-flight
// Y b128 loads, ~80 peak live -> fits the 128-VGPR default budget.
template<int LH>
__device__ __forceinline__ void phaseB_half(
    const h4* __restrict__ A4, const h8* __restrict__ Y8,
    float* __restrict__ out, const int tt, const int bp, const int m,
    float& vmax)
{
    float X0[12], X1[12];
    #pragma unroll
    for (int i = 0; i < 12; ++i) { X0[i] = 0.f; X1[i] = 0.f; }
    #pragma unroll 1
    for (int sq = 0; sq < 6; ++sq) {
        const int ab = (4 * sq) * AP_ + tt;
        const h4 q0 = A4[ab], q1 = A4[ab + AP_], q2 = A4[ab + 2 * AP_], q3 = A4[ab + 3 * AP_];
        const int ybase = (bp * 6 + sq) * NYR_ + tt;
        #pragma unroll
        for (int lo = 0; lo < 12; ++lo) {
            const int l = LH * 12 + lo;          // compile-time (lo unrolled)
            h2 f01; f01.x = (_Float16)FR[l]; f01.y = (_Float16)FG[l];
            h2 f23; f23.x = (_Float16)FB[l]; f23.y = (_Float16)FC[l];
            const float g0 = fdot2(h2{q0.x,q0.y}, f01, fdot2(h2{q0.z,q0.w}, f23, 0.f));
            const float g1 = fdot2(h2{q1.x,q1.y}, f01, fdot2(h2{q1.z,q1.w}, f23, 0.f));
            const float g2 = fdot2(h2{q2.x,q2.y}, f01, fdot2(h2{q2.z,q2.w}, f23, 0.f));
            const float g3 = fdot2(h2{q3.x,q3.y}, f01, fdot2(h2{q3.z,q3.w}, f23, 0.f));
            h2 G01; G01.x = (_Float16)g0; G01.y = (_Float16)g1;
            h2 G23; G23.x = (_Float16)g2; G23.y = (_Float16)g3;
            const h8 y = Y8[ybase + l];
            X0[lo] = fdot2(G01, h2{y[0],y[1]}, fdot2(G23, h2{y[2],y[3]}, X0[lo]));
            X1[lo] = fdot2(G01, h2{y[4],y[5]}, fdot2(G23, h2{y[6],y[7]}, X1[lo]));
            if ((lo % 6) == 5) __builtin_amdgcn_sched_barrier(0);
        }
    }
    float4* o0 = reinterpret_cast<float4*>(out + (((2*bp    ) * M_ + m) * N_ + tt) * L_) + LH * 3;
    float4* o1 = reinterpret_cast<float4*>(out + (((2*bp + 1) * M_ + m) * N_ + tt) * L_) + LH * 3;
    #pragma unroll
    for (int i = 0; i < 3; ++i) {
        float4 v0, v1;
        v0.x = X0[4*i+0]; v0.y = X0[4*i+1]; v0.z = X0[4*i+2]; v0.w = X0[4*i+3];
        v1.x = X1[4*i+0]; v1.y = X1[4*i+1]; v1.z = X1[4*i+2]; v1.w = X1[4*i+3];
        vmax = fmaxf(vmax, fmaxf(fmaxf(v0.x, v0.y), fmaxf(v0.z, v0.w)));
        vmax = fmaxf(vmax, fmaxf(fmaxf(v1.x, v1.y), fmaxf(v1.z, v1.w)));
        o0[i] = v0;
        o1[i] = v1;
    }
}

// R20: R19 (bp-split) confirmed the steady-state live-set theory (WRITE
// 110->83MB, dur 110->95us) but VGPR still capped at 128 with residual
// spill. Fix the mismatch structurally: 1024 threads. LDS still forces
// 1 block/CU -> exactly 4 waves/SIMD, which is the allocator's DEFAULT
// 128-VGPR occupancy target — cap and demand finally agree. Per-thread
// work halves again: phase A 4-way split (bp = th&1, sq-half = th>>1),
// phase B 4-way split (bp = th&1, l-half = th>>1), staging 4-way
// parallel (x{b0,b1}/x{b2,b3} as h2 halves + weights split 11/11).
// Bonus: 4 waves/SIMD doubles TLP latency hiding (the R12 goal).
__global__ __launch_bounds__(1024)
void cassi_fused(
    const float* __restrict__ x,
    const float* __restrict__ wr, const float* __restrict__ wg,
    const float* __restrict__ wb, const float* __restrict__ wc,
    float* __restrict__ out, float* __restrict__ bmax_out)
{
    __shared__ __align__(16) char lds_raw[LDS_BYTES];   // static descriptor: 154KB
    h4* A4  = reinterpret_cast<h4*>(lds_raw);
    h2* XT2 = reinterpret_cast<h2*>(lds_raw) + XT_OFF_H2;
    h4* Y4  = reinterpret_cast<h4*>(lds_raw) + Y_OFF_H4;
    h8* Y8  = reinterpret_cast<h8*>(lds_raw) + Y_OFF_H8;
    float* wmax = reinterpret_cast<float*>(lds_raw + WMAX_OFF);

    const int t  = threadIdx.x;
    const int tt = t & 255;        // column / lane-within-quarter
    const int th = t >> 8;         // quarter index (0..3)
    const int m  = blockIdx.x;

    // ---- Staging (4-way parallel) ----
    // zero A pad rows s=22,23 (514 h4): 1024 threads, one guarded store.
    {
        h4 z; z.x = z.y = z.z = z.w = (_Float16)0.f;
        if (t < 514) A4[S_ * AP_ + t] = z;
    }
    if (th == 0 || th == 3) {
        // x: th0 stages {b0,b1}, th3 stages {b2,b3} -> h2 halves of XT cells.
        const int b0 = (th == 0) ? 0 : 2;
        const int hh = (th == 0) ? 0 : 1;
        const float4* xa = reinterpret_cast<const float4*>(x + (((b0    ) * M_ + m) * N_ + tt) * L_);
        const float4* xb = reinterpret_cast<const float4*>(x + (((b0 + 1) * M_ + m) * N_ + tt) * L_);
        #pragma unroll
        for (int i = 0; i < 6; ++i) {
            const float4 va = xa[i], vb = xb[i];
            h2 c0; c0.x=(_Float16)va.x; c0.y=(_Float16)vb.x;
            h2 c1; c1.x=(_Float16)va.y; c1.y=(_Float16)vb.y;
            h2 c2; c2.x=(_Float16)va.z; c2.y=(_Float16)vb.z;
            h2 c3; c3.x=(_Float16)va.w; c3.y=(_Float16)vb.w;
            XT2[(tt * XTP_ + 4 * i + 0) * 2 + hh] = c0;
            XT2[(tt * XTP_ + 4 * i + 1) * 2 + hh] = c1;
            XT2[(tt * XTP_ + 4 * i + 2) * 2 + hh] = c2;
            XT2[(tt * XTP_ + 4 * i + 3) * 2 + hh] = c3;
            __builtin_amdgcn_sched_barrier(0);
        }
    } else {
        // weights: th1 rows i=0..10, th2 rows i=11..21; coalesced, normalized,
        // h4-packed A[s][n].
        const float* wrm = wr + m * (N_ * S_);
        const float* wgm = wg + m * (N_ * S_);
        const float* wbm = wb + m * (N_ * S_);
        const float* wcm = wc + m * (N_ * S_);
        const int i0 = (th == 1) ? 0 : 11;
        const int i1 = (th == 1) ? 11 : S_;
        #pragma unroll 1
        for (int i = i0; i < i1; ++i) {
            const int f = i * 256 + tt;
            const float r = wrm[f], g = wgm[f], u = wbm[f], v = wcm[f];
            const int n = f / S_, s = f - n * S_;
            const float inv = 1.f / (r + g + u + v);
            h4 p;
            p.x = (_Float16)(r * inv); p.y = (_Float16)(g * inv);
            p.z = (_Float16)(u * inv); p.w = (_Float16)(v * inv);
            A4[s * AP_ + n] = p;
        }
    }
    __syncthreads();

    // ---- Phase A (4-way split): thread (tt,th) gathers Y for b-pair bp =
    // th&1, sq range sqh*3..sqh*3+2 (sqh = th>>1). Acc 8 regs (16 on tail
    // waves). Waves 0/4/8/12 (tt < 64) run the dual main+tail version; the
    // rest the lean one (idx = tt-l always valid). Wave-uniform branch.
    {
        const int bp  = th & 1;
        const int sq0 = (th >> 1) * 3;
        if (tt < 64) {
            #pragma unroll 1
            for (int sqo = 0; sqo < 3; ++sqo) {
                const int sq = sq0 + sqo;
                float4 aM0, aM1, aT0, aT1;
                aM0.x=aM0.y=aM0.z=aM0.w=0.f; aM1=aM0; aT0=aM0; aT1=aM0;
                #pragma unroll
                for (int l = 0; l < L_; ++l) {
                    h2 f01; f01.x = (_Float16)FR[l]; f01.y = (_Float16)FG[l];
                    h2 f23; f23.x = (_Float16)FB[l]; f23.y = (_Float16)FC[l];
                    const bool mn = (l <= tt);
                    const int idx = mn ? (tt - l) : (256 + tt - l);
                    const float mm = mn ? 1.f : 0.f;
                    const int ab = (4 * sq) * AP_ + idx;
                    const h4 p0 = A4[ab], p1 = A4[ab + AP_], p2 = A4[ab + 2 * AP_], p3 = A4[ab + 3 * AP_];
                    const h2 xq = XT2[(idx * XTP_ + l) * 2 + bp];
                    const float g0 = fdot2(h2{p0.x,p0.y}, f01, fdot2(h2{p0.z,p0.w}, f23, 0.f));
                    const float g1 = fdot2(h2{p1.x,p1.y}, f01, fdot2(h2{p1.z,p1.w}, f23, 0.f));
                    const float g2 = fdot2(h2{p2.x,p2.y}, f01, fdot2(h2{p2.z,p2.w}, f23, 0.f));
                    const float g3 = fdot2(h2{p3.x,p3.y}, f01, fdot2(h2{p3.z,p3.w}, f23, 0.f));
                    const float gm0 = g0 * mm, gt0 = g0 - gm0;
                    const float gm1 = g1 * mm, gt1 = g1 - gm1;
                    const float gm2 = g2 * mm, gt2 = g2 - gm2;
                    const float gm3 = g3 * mm, gt3 = g3 - gm3;
                    const float xv0 = (float)xq.x, xv1 = (float)xq.y;
                    aM0.x += gm0 * xv0; aT0.x += gt0 * xv0;
                    aM0.y += gm1 * xv0; aT0.y += gt1 * xv0;
                    aM0.z += gm2 * xv0; aT0.z += gt2 * xv0;
                    aM0.w += gm3 * xv0; aT0.w += gt3 * xv0;
                    aM1.x += gm0 * xv1; aT1.x += gt0 * xv1;
                    aM1.y += gm1 * xv1; aT1.y += gt1 * xv1;
                    aM1.z += gm2 * xv1; aT1.z += gt2 * xv1;
                    aM1.w += gm3 * xv1; aT1.w += gt3 * xv1;
                    if ((l & 3) == 3) __builtin_amdgcn_sched_barrier(0);
                }
                const int cell = (bp * 6 + sq) * NYR_;
                h4 pm0, pm1;
                pm0.x=(_Float16)aM0.x; pm0.y=(_Float16)aM0.y; pm0.z=(_Float16)aM0.z; pm0.w=(_Float16)aM0.w;
                pm1.x=(_Float16)aM1.x; pm1.y=(_Float16)aM1.y; pm1.z=(_Float16)aM1.z; pm1.w=(_Float16)aM1.w;
                Y4[(cell + tt) * 2 + 0] = pm0;
                Y4[(cell + tt) * 2 + 1] = pm1;
                if (tt < 23) {
                    h4 pt0, pt1;
                    pt0.x=(_Float16)aT0.x; pt0.y=(_Float16)aT0.y; pt0.z=(_Float16)aT0.z; pt0.w=(_Float16)aT0.w;
                    pt1.x=(_Float16)aT1.x; pt1.y=(_Float16)aT1.y; pt1.z=(_Float16)aT1.z; pt1.w=(_Float16)aT1.w;
                    Y4[(cell + 256 + tt) * 2 + 0] = pt0;
                    Y4[(cell + 256 + tt) * 2 + 1] = pt1;
                }
            }
        } else {
            #pragma unroll 1
            for (int sqo = 0; sqo < 3; ++sqo) {
                const int sq = sq0 + sqo;
                float4 aM0, aM1;
                aM0.x=aM0.y=aM0.z=aM0.w=0.f; aM1=aM0;
                #pragma unroll
                for (int l = 0; l < L_; ++l) {
                    h2 f01; f01.x = (_Float16)FR[l]; f01.y = (_Float16)FG[l];
                    h2 f23; f23.x = (_Float16)FB[l]; f23.y = (_Float16)FC[l];
                    const int idx = tt - l;      // tt >= 64 -> always >= 41
                    const int ab = (4 * sq) * AP_ + idx;
                    const h4 p0 = A4[ab], p1 = A4[ab + AP_], p2 = A4[ab + 2 * AP_], p3 = A4[ab + 3 * AP_];
                    const h2 xq = XT2[(idx * XTP_ + l) * 2 + bp];
                    const float g0 = fdot2(h2{p0.x,p0.y}, f01, fdot2(h2{p0.z,p0.w}, f23, 0.f));
                    const float g1 = fdot2(h2{p1.x,p1.y}, f01, fdot2(h2{p1.z,p1.w}, f23, 0.f));
                    const float g2 = fdot2(h2{p2.x,p2.y}, f01, fdot2(h2{p2.z,p2.w}, f23, 0.f));
                    const float g3 = fdot2(h2{p3.x,p3.y}, f01, fdot2(h2{p3.z,p3.w}, f23, 0.f));
                    const float xv0 = (float)xq.x, xv1 = (float)xq.y;
                    aM0.x += g0 * xv0; aM1.x += g0 * xv1;
                    aM0.y += g1 * xv0; aM1.y += g1 * xv1;
                    aM0.z += g2 * xv0; aM1.z += g2 * xv1;
                    aM0.w += g3 * xv0; aM1.w += g3 * xv1;
                    if ((l % 6) == 5) __builtin_amdgcn_sched_barrier(0);
                }
                const int cell = (bp * 6 + sq) * NYR_;
                h4 pm0, pm1;
                pm0.x=(_Float16)aM0.x; pm0.y=(_Float16)aM0.y; pm0.z=(_Float16)aM0.z; pm0.w=(_Float16)aM0.w;
                pm1.x=(_Float16)aM1.x; pm1.y=(_Float16)aM1.y; pm1.z=(_Float16)aM1.z; pm1.w=(_Float16)aM1.w;
                Y4[(cell + tt) * 2 + 0] = pm0;
                Y4[(cell + tt) * 2 + 1] = pm1;
            }
        }
    }
    __syncthreads();

    // ---- Phase B (4-way split): bp = th&1, l-half = th>>1. One instance
    // per thread. Wave-uniform branch on th.
    float vmax = 0.f;
    {
        const int bp = th & 1;
        if ((th >> 1) == 0) phaseB_half<0>(A4, Y8, out, tt, bp, m, vmax);
        else                phaseB_half<1>(A4, Y8, out, tt, bp, m, vmax);
    }

    #pragma unroll
    for (int off = 32; off > 0; off >>= 1)
        vmax = fmaxf(vmax, __shfl_xor(vmax, off, 64));
    if ((t & 63) == 0) wmax[t >> 6] = vmax;
    __syncthreads();
    if (t == 0) {
        float v = wmax[0];
        #pragma unroll
        for (int w = 1; w < 16; ++w) v = fmaxf(v, wmax[w]);
        bmax_out[m] = v;
    }
}

// Normalize; each block re-reduces the 256 per-block maxes itself.
__global__ __launch_bounds__(256) void cassi_norm(float* __restrict__ out,
                                                  const float* __restrict__ bmax)
{
    __shared__ float wm[4];
    const int t = threadIdx.x;
    float v = bmax[t];
    #pragma unroll
    for (int off = 32; off > 0; off >>= 1)
        v = fmaxf(v, __shfl_xor(v, off, 64));
    if ((t & 63) == 0) wm[t >> 6] = v;
    __syncthreads();
    const float inv = 1.f / fmaxf(fmaxf(wm[0], wm[1]), fmaxf(wm[2], wm[3]));
    const int i = (blockIdx.x * 256 + t) * 4;
    float4 q = *reinterpret_cast<float4*>(out + i);
    q.x *= inv; q.y *= inv; q.z *= inv; q.w *= inv;
    *reinterpret_cast<float4*>(out + i) = q;
}

extern "C" void kernel_launch(void* const* d_in, const int* in_sizes, int n_in,
                              void* d_out, int out_size, void* d_ws, size_t ws_size,
                              hipStream_t stream) {
    const float* x  = (const float*)d_in[0];
    const float* wr = (const float*)d_in[1];
    const float* wg = (const float*)d_in[2];
    const float* wb = (const float*)d_in[3];
    const float* wc = (const float*)d_in[4];
    float* out  = (float*)d_out;
    float* bmax = (float*)d_ws;          // 256 per-block maxes

    cassi_fused<<<M_, 1024, 0, stream>>>(x, wr, wg, wb, wc, out, bmax);
    const int n4blocks = (B_ * M_ * N_ * L_) / 4 / 256;     // 6144, exact
    cassi_norm<<<n4blocks, 256, 0, stream>>>(out, bmax);
}

// Round 11
// 173.351 us; speedup vs baseline: 1.3513x; 1.3513x over previous
//
#include <hip/hip_runtime.h>

typedef _Float16 h8 __attribute__((ext_vector_type(8)));
typedef _Float16 h4 __attribute__((ext_vector_type(4)));
typedef _Float16 h2 __attribute__((ext_vector_type(2)));

// Problem constants (reference: B,M,N,L,S,KERN = 4,256,256,24,22,256; KERN==M → tile is identity)
constexpr int B_ = 4, M_ = 256, N_ = 256, L_ = 24, S_ = 22;
constexpr int SP_  = 24;    // shots padded to 24 (2 zero rows) for clean s-quads
constexpr int AP_  = 257;   // A4 [s][n] row pitch in h4 units (odd -> b64 reads 2-way, free)
constexpr int XTP_ = 25;    // XT2 [n][l] row pitch in h2 (4B) cells (25-dword stride, conflict-free)
constexpr int NYR_ = 280;   // Y rows (279 used: 256 main + 23 tail)

// LDS layout (bytes) — sized for 2 blocks/CU (<= 81,920 each):
constexpr int A4_BYTES = SP_ * AP_ * 8;            // 49,344  A[s][n] h4 over c
constexpr int XT_BYTES = N_ * XTP_ * 4;            // 25,600  x[n][l] h2 over this block's b-pair
constexpr int Y_BYTES  = NYR_ * 16;                //  4,480  Y[n'] 16B cells (2 h4), ONE sq at a time
constexpr int XT_OFF   = A4_BYTES;                 // 49,344
constexpr int Y_OFF    = XT_OFF + XT_BYTES;        // 74,944 (16B-aligned)
constexpr int WMAX_OFF = Y_OFF + Y_BYTES;          // 79,424
constexpr int LDS_BYTES = WMAX_OFF + 32;           // 79,456 <= 81,920  -> 2 blocks/CU
constexpr int XT_OFF_H2 = XT_OFF / 4;              // 12,336
constexpr int Y_OFF_H4  = Y_OFF / 8;               //  9,368
constexpr int Y_OFF_H8  = Y_OFF / 16;              //  4,684

// Color bases as COMPILE-TIME constants (validated R6/R8/R9/R10):
constexpr float FR[L_] = {  // mu = 620
    6.252150e-05f, 1.904358e-04f, 5.418690e-04f, 1.440515e-03f, 3.577400e-03f,
    8.299750e-03f, 1.798893e-02f, 3.642490e-02f, 6.890060e-02f, 1.217600e-01f,
    2.010120e-01f, 3.100190e-01f, 4.466857e-01f, 6.012587e-01f, 7.560710e-01f,
    8.881955e-01f, 9.747661e-01f, 9.993953e-01f, 9.572367e-01f, 8.565352e-01f,
    7.160078e-01f, 5.591580e-01f, 4.079402e-01f, 2.780373e-01f};
constexpr float FG[L_] = {  // mu = 550
    1.110900e-02f, 2.348440e-02f, 4.638000e-02f, 8.557090e-02f, 1.474900e-01f,
    2.374920e-01f, 3.572560e-01f, 5.020580e-01f, 6.591400e-01f, 8.084270e-01f,
    9.262975e-01f, 9.915296e-01f, 9.915296e-01f, 9.262975e-01f, 8.084270e-01f,
    6.591400e-01f, 5.020580e-01f, 3.572560e-01f, 2.374920e-01f, 1.474900e-01f,
    8.557090e-02f, 4.638000e-02f, 2.348440e-02f, 1.110900e-02f};
constexpr float FB[L_] = {  // mu = 450 (pairs with wb)
    6.065307e-01f, 7.609727e-01f, 8.919300e-01f, 9.766475e-01f, 9.990553e-01f,
    9.547420e-01f, 8.523698e-01f, 7.109096e-01f, 5.539184e-01f, 4.032022e-01f,
    2.741855e-01f, 1.741852e-01f, 1.033776e-01f, 5.731640e-02f, 2.968800e-02f,
    1.436580e-02f, 6.494090e-03f, 2.742560e-03f, 1.079230e-03f, 3.988070e-04f,
    1.369660e-04f, 4.417250e-05f, 1.327420e-05f, 3.726650e-06f};
constexpr float FC[L_] = {  // mu = 500 (pairs with wc)
    1.353353e-01f, 2.204053e-01f, 3.353338e-01f, 4.766271e-01f, 6.328849e-01f,
    7.850828e-01f, 9.098110e-01f, 9.849909e-01f, 9.962264e-01f, 9.413024e-01f,
    8.308921e-01f, 6.851808e-01f, 5.278508e-01f, 3.798934e-01f, 2.554222e-01f,
    1.604349e-01f, 9.414200e-02f, 5.160780e-02f, 2.642960e-02f, 1.264440e-02f,
    5.651680e-03f, 2.359870e-03f, 9.205430e-04f, 3.354630e-04f};

__device__ __forceinline__ float fdot2(h2 a, h2 b, float c) {
    return __builtin_amdgcn_fdot2(a, b, c, false);
}

// R21: R20 (1024thr -> VGPR 64, WRITE 245MB) completed the allocator model:
// budget = 65536/workgroup_size (default 2 workgroups/CU target; attributes
// don't override it). So the ONLY shape with a >=256 budget is <=256
// threads, and 2 wg/CU is only real if LDS <= 80KB. R21 aligns everything:
// 256 threads (budget 256), LDS 79,456B (A full + XT for one b-pair + a
// SINGLE-sq Y buffer reused across 6 A/B pass pairs), grid 512 = 2 blocks
// per m-row split by b-pair -> 2 blocks/CU resident -> 8 waves/CU =
// 2 waves/SIMD, with each block's barriers hidden by the other block.
// Live set: X0[24]+X1[24] (48) + pass working (~45) ~= 115 -> no spill.
// All sched_barriers removed (no longer fighting the allocator).
__global__ __launch_bounds__(256)
void cassi_fused(
    const float* __restrict__ x,
    const float* __restrict__ wr, const float* __restrict__ wg,
    const float* __restrict__ wb, const float* __restrict__ wc,
    float* __restrict__ out, float* __restrict__ bmax_out)
{
    __shared__ __align__(16) char lds_raw[LDS_BYTES];
    h4* A4  = reinterpret_cast<h4*>(lds_raw);
    h2* XT2 = reinterpret_cast<h2*>(lds_raw) + XT_OFF_H2;
    h4* Y4  = reinterpret_cast<h4*>(lds_raw) + Y_OFF_H4;
    h8* Y8  = reinterpret_cast<h8*>(lds_raw) + Y_OFF_H8;
    float* wmax = reinterpret_cast<float*>(lds_raw + WMAX_OFF);

    const int t  = threadIdx.x;          // 0..255: column
    const int m  = blockIdx.x >> 1;      // row
    const int bp = blockIdx.x & 1;       // b-pair: handles b = 2bp, 2bp+1
    const int b0 = 2 * bp, b1 = 2 * bp + 1;

    // ---- Staging ----
    // zero A pad rows s=22,23 (514 h4): 256 threads x2 + 2 guarded.
    {
        h4 z; z.x = z.y = z.z = z.w = (_Float16)0.f;
        A4[S_ * AP_ + t] = z;
        A4[S_ * AP_ + 256 + t] = z;
        if (t < 2) A4[S_ * AP_ + 512 + t] = z;
    }
    // x: thread t stages column n=t for THIS block's two b -> XT2[n][l] h2.
    {
        const float4* xa = reinterpret_cast<const float4*>(x + ((b0 * M_ + m) * N_ + t) * L_);
        const float4* xb = reinterpret_cast<const float4*>(x + ((b1 * M_ + m) * N_ + t) * L_);
        #pragma unroll
        for (int i = 0; i < 6; ++i) {
            const float4 va = xa[i], vb = xb[i];
            h2 c0; c0.x=(_Float16)va.x; c0.y=(_Float16)vb.x;
            h2 c1; c1.x=(_Float16)va.y; c1.y=(_Float16)vb.y;
            h2 c2; c2.x=(_Float16)va.z; c2.y=(_Float16)vb.z;
            h2 c3; c3.x=(_Float16)va.w; c3.y=(_Float16)vb.w;
            XT2[t * XTP_ + 4 * i + 0] = c0;
            XT2[t * XTP_ + 4 * i + 1] = c1;
            XT2[t * XTP_ + 4 * i + 2] = c2;
            XT2[t * XTP_ + 4 * i + 3] = c3;
        }
    }
    // weights: coalesced, normalized once, h4-packed A[s][n] (both blocks of
    // a row stage this; second reader hits L2/L3).
    {
        const float* wrm = wr + m * (N_ * S_);
        const float* wgm = wg + m * (N_ * S_);
        const float* wbm = wb + m * (N_ * S_);
        const float* wcm = wc + m * (N_ * S_);
        #pragma unroll 1
        for (int i = 0; i < S_; ++i) {
            const int f = i * 256 + t;
            const float r = wrm[f], g = wgm[f], u = wbm[f], v = wcm[f];
            const int n = f / S_, s = f - n * S_;
            const float inv = 1.f / (r + g + u + v);
            h4 p;
            p.x = (_Float16)(r * inv); p.y = (_Float16)(g * inv);
            p.z = (_Float16)(u * inv); p.w = (_Float16)(v * inv);
            A4[s * AP_ + n] = p;
        }
    }
    __syncthreads();

    // ---- 6 alternating pass pairs: A(sq) fills Y, B(sq) consumes it.
    // X accumulators live across all passes (48 regs).
    float X0[L_], X1[L_];
    #pragma unroll
    for (int l = 0; l < L_; ++l) { X0[l] = 0.f; X1[l] = 0.f; }
    float vmax = 0.f;

    #pragma unroll 1
    for (int sq = 0; sq < 6; ++sq) {
        // ---- A-pass: Y[n'] gather for this sq. Wave 0 (t<64) dual
        // main+tail; waves 1-3 lean (idx = t-l >= 41). Wave-uniform branch.
        if (t < 64) {
            float4 aM0, aM1, aT0, aT1;
            aM0.x=aM0.y=aM0.z=aM0.w=0.f; aM1=aM0; aT0=aM0; aT1=aM0;
            #pragma unroll
            for (int l = 0; l < L_; ++l) {
                h2 f01; f01.x = (_Float16)FR[l]; f01.y = (_Float16)FG[l];
                h2 f23; f23.x = (_Float16)FB[l]; f23.y = (_Float16)FC[l];
                const bool mn = (l <= t);
                const int idx = mn ? (t - l) : (256 + t - l);
                const float mm = mn ? 1.f : 0.f;
                const int ab = (4 * sq) * AP_ + idx;
                const h4 p0 = A4[ab], p1 = A4[ab + AP_], p2 = A4[ab + 2 * AP_], p3 = A4[ab + 3 * AP_];
                const h2 xq = XT2[idx * XTP_ + l];
                const float g0 = fdot2(h2{p0.x,p0.y}, f01, fdot2(h2{p0.z,p0.w}, f23, 0.f));
                const float g1 = fdot2(h2{p1.x,p1.y}, f01, fdot2(h2{p1.z,p1.w}, f23, 0.f));
                const float g2 = fdot2(h2{p2.x,p2.y}, f01, fdot2(h2{p2.z,p2.w}, f23, 0.f));
                const float g3 = fdot2(h2{p3.x,p3.y}, f01, fdot2(h2{p3.z,p3.w}, f23, 0.f));
                const float gm0 = g0 * mm, gt0 = g0 - gm0;
                const float gm1 = g1 * mm, gt1 = g1 - gm1;
                const float gm2 = g2 * mm, gt2 = g2 - gm2;
                const float gm3 = g3 * mm, gt3 = g3 - gm3;
                const float xv0 = (float)xq.x, xv1 = (float)xq.y;
                aM0.x += gm0 * xv0; aT0.x += gt0 * xv0;
                aM0.y += gm1 * xv0; aT0.y += gt1 * xv0;
                aM0.z += gm2 * xv0; aT0.z += gt2 * xv0;
                aM0.w += gm3 * xv0; aT0.w += gt3 * xv0;
                aM1.x += gm0 * xv1; aT1.x += gt0 * xv1;
                aM1.y += gm1 * xv1; aT1.y += gt1 * xv1;
                aM1.z += gm2 * xv1; aT1.z += gt2 * xv1;
                aM1.w += gm3 * xv1; aT1.w += gt3 * xv1;
            }
            h4 pm0, pm1;
            pm0.x=(_Float16)aM0.x; pm0.y=(_Float16)aM0.y; pm0.z=(_Float16)aM0.z; pm0.w=(_Float16)aM0.w;
            pm1.x=(_Float16)aM1.x; pm1.y=(_Float16)aM1.y; pm1.z=(_Float16)aM1.z; pm1.w=(_Float16)aM1.w;
            Y4[t * 2 + 0] = pm0;
            Y4[t * 2 + 1] = pm1;
            if (t < 23) {
                h4 pt0, pt1;
                pt0.x=(_Float16)aT0.x; pt0.y=(_Float16)aT0.y; pt0.z=(_Float16)aT0.z; pt0.w=(_Float16)aT0.w;
                pt1.x=(_Float16)aT1.x; pt1.y=(_Float16)aT1.y; pt1.z=(_Float16)aT1.z; pt1.w=(_Float16)aT1.w;
                Y4[(256 + t) * 2 + 0] = pt0;
                Y4[(256 + t) * 2 + 1] = pt1;
            }
        } else {
            float4 aM0, aM1;
            aM0.x=aM0.y=aM0.z=aM0.w=0.f; aM1=aM0;
            #pragma unroll
            for (int l = 0; l < L_; ++l) {
                h2 f01; f01.x = (_Float16)FR[l]; f01.y = (_Float16)FG[l];
                h2 f23; f23.x = (_Float16)FB[l]; f23.y = (_Float16)FC[l];
                const int idx = t - l;      // t >= 64 -> always >= 41
                const int ab = (4 * sq) * AP_ + idx;
                const h4 p0 = A4[ab], p1 = A4[ab + AP_], p2 = A4[ab + 2 * AP_], p3 = A4[ab + 3 * AP_];
                const h2 xq = XT2[idx * XTP_ + l];
                const float g0 = fdot2(h2{p0.x,p0.y}, f01, fdot2(h2{p0.z,p0.w}, f23, 0.f));
                const float g1 = fdot2(h2{p1.x,p1.y}, f01, fdot2(h2{p1.z,p1.w}, f23, 0.f));
                const float g2 = fdot2(h2{p2.x,p2.y}, f01, fdot2(h2{p2.z,p2.w}, f23, 0.f));
                const float g3 = fdot2(h2{p3.x,p3.y}, f01, fdot2(h2{p3.z,p3.w}, f23, 0.f));
                const float xv0 = (float)xq.x, xv1 = (float)xq.y;
                aM0.x += g0 * xv0; aM1.x += g0 * xv1;
                aM0.y += g1 * xv0; aM1.y += g1 * xv1;
                aM0.z += g2 * xv0; aM1.z += g2 * xv1;
                aM0.w += g3 * xv0; aM1.w += g3 * xv1;
            }
            h4 pm0, pm1;
            pm0.x=(_Float16)aM0.x; pm0.y=(_Float16)aM0.y; pm0.z=(_Float16)aM0.z; pm0.w=(_Float16)aM0.w;
            pm1.x=(_Float16)aM1.x; pm1.y=(_Float16)aM1.y; pm1.z=(_Float16)aM1.z; pm1.w=(_Float16)aM1.w;
            Y4[t * 2 + 0] = pm0;
            Y4[t * 2 + 1] = pm1;
        }
        __syncthreads();

        // ---- B-pass: X[b][t][l] += sum over this sq's 4 shots.
        {
            const int ab = (4 * sq) * AP_ + t;
            const h4 q0 = A4[ab], q1 = A4[ab + AP_], q2 = A4[ab + 2 * AP_], q3 = A4[ab + 3 * AP_];
            #pragma unroll
            for (int l = 0; l < L_; ++l) {
                h2 f01; f01.x = (_Float16)FR[l]; f01.y = (_Float16)FG[l];
                h2 f23; f23.x = (_Float16)FB[l]; f23.y = (_Float16)FC[l];
                const float g0 = fdot2(h2{q0.x,q0.y}, f01, fdot2(h2{q0.z,q0.w}, f23, 0.f));
                const float g1 = fdot2(h2{q1.x,q1.y}, f01, fdot2(h2{q1.z,q1.w}, f23, 0.f));
                const float g2 = fdot2(h2{q2.x,q2.y}, f01, fdot2(h2{q2.z,q2.w}, f23, 0.f));
                const float g3 = fdot2(h2{q3.x,q3.y}, f01, fdot2(h2{q3.z,q3.w}, f23, 0.f));
                h2 G01; G01.x = (_Float16)g0; G01.y = (_Float16)g1;
                h2 G23; G23.x = (_Float16)g2; G23.y = (_Float16)g3;
                const h8 y = Y8[t + l];
                X0[l] = fdot2(G01, h2{y[0],y[1]}, fdot2(G23, h2{y[2],y[3]}, X0[l]));
                X1[l] = fdot2(G01, h2{y[4],y[5]}, fdot2(G23, h2{y[6],y[7]}, X1[l]));
            }
        }
        __syncthreads();   // Y buffer free for next sq
    }

    // ---- Output: contiguous 96B burst per (b, row t) + running max.
    {
        float4* o0 = reinterpret_cast<float4*>(out + ((b0 * M_ + m) * N_ + t) * L_);
        float4* o1 = reinterpret_cast<float4*>(out + ((b1 * M_ + m) * N_ + t) * L_);
        #pragma unroll
        for (int i = 0; i < 6; ++i) {
            float4 v0, v1;
            v0.x = X0[4*i+0]; v0.y = X0[4*i+1]; v0.z = X0[4*i+2]; v0.w = X0[4*i+3];
            v1.x = X1[4*i+0]; v1.y = X1[4*i+1]; v1.z = X1[4*i+2]; v1.w = X1[4*i+3];
            vmax = fmaxf(vmax, fmaxf(fmaxf(v0.x, v0.y), fmaxf(v0.z, v0.w)));
            vmax = fmaxf(vmax, fmaxf(fmaxf(v1.x, v1.y), fmaxf(v1.z, v1.w)));
            o0[i] = v0;
            o1[i] = v1;
        }
    }

    #pragma unroll
    for (int off = 32; off > 0; off >>= 1)
        vmax = fmaxf(vmax, __shfl_xor(vmax, off, 64));
    if ((t & 63) == 0) wmax[t >> 6] = vmax;
    __syncthreads();
    if (t == 0)
        bmax_out[blockIdx.x] = fmaxf(fmaxf(wmax[0], wmax[1]), fmaxf(wmax[2], wmax[3]));
}

// Normalize; each block re-reduces the 512 per-block maxes itself.
__global__ __launch_bounds__(256) void cassi_norm(float* __restrict__ out,
                                                  const float* __restrict__ bmax)
{
    __shared__ float wm[4];
    const int t = threadIdx.x;
    float v = fmaxf(bmax[t], bmax[t + 256]);
    #pragma unroll
    for (int off = 32; off > 0; off >>= 1)
        v = fmaxf(v, __shfl_xor(v, off, 64));
    if ((t & 63) == 0) wm[t >> 6] = v;
    __syncthreads();
    const float inv = 1.f / fmaxf(fmaxf(wm[0], wm[1]), fmaxf(wm[2], wm[3]));
    const int i = (blockIdx.x * 256 + t) * 4;
    float4 q = *reinterpret_cast<float4*>(out + i);
    q.x *= inv; q.y *= inv; q.z *= inv; q.w *= inv;
    *reinterpret_cast<float4*>(out + i) = q;
}

extern "C" void kernel_launch(void* const* d_in, const int* in_sizes, int n_in,
                              void* d_out, int out_size, void* d_ws, size_t ws_size,
                              hipStream_t stream) {
    const float* x  = (const float*)d_in[0];
    const float* wr = (const float*)d_in[1];
    const float* wg = (const float*)d_in[2];
    const float* wb = (const float*)d_in[3];
    const float* wc = (const float*)d_in[4];
    float* out  = (float*)d_out;
    float* bmax = (float*)d_ws;          // 512 per-block maxes (2KB)

    cassi_fused<<<2 * M_, 256, 0, stream>>>(x, wr, wg, wb, wc, out, bmax);
    const int n4blocks = (B_ * M_ * N_ * L_) / 4 / 256;     // 6144, exact
    cassi_norm<<<n4blocks, 256, 0, stream>>>(out, bmax);
}

// Round 13
// 171.015 us; speedup vs baseline: 1.3697x; 1.0137x over previous
//
#include <hip/hip_runtime.h>

typedef _Float16 h8 __attribute__((ext_vector_type(8)));
typedef _Float16 h4 __attribute__((ext_vector_type(4)));
typedef _Float16 h2 __attribute__((ext_vector_type(2)));

// Problem constants (reference: B,M,N,L,S,KERN = 4,256,256,24,22,256; KERN==M → tile is identity)
constexpr int B_ = 4, M_ = 256, N_ = 256, L_ = 24, S_ = 22;
constexpr int SP_  = 24;    // shots padded to 24 (2 zero rows) for clean s-quads
constexpr int AP_  = 257;   // A4 [s][n] row pitch in h4 units (odd -> b64 reads 2-way, free)
constexpr int XTP_ = 25;    // XT2 [n][l] row pitch in h2 (4B) cells (25-dword stride, conflict-free)
constexpr int NYR_ = 280;   // Y rows (279 used: 256 main + 23 tail)

// LDS layout (bytes) — sized for 2 blocks/CU (<= 81,920 each):
constexpr int A4_BYTES = SP_ * AP_ * 8;            // 49,344  A[s][n] h4 over c
constexpr int XT_BYTES = N_ * XTP_ * 4;            // 25,600  x[n][l] h2 over this block's b-pair
constexpr int Y_BYTES  = NYR_ * 16;                //  4,480  Y[n'] 16B cells (2 h4), ONE sq at a time
constexpr int XT_OFF   = A4_BYTES;                 // 49,344
constexpr int Y_OFF    = XT_OFF + XT_BYTES;        // 74,944 (16B-aligned)
constexpr int WMAX_OFF = Y_OFF + Y_BYTES;          // 79,424
constexpr int LDS_BYTES = WMAX_OFF + 32;           // 79,456 <= 81,920  -> 2 blocks/CU
constexpr int XT_OFF_H2 = XT_OFF / 4;              // 12,336
constexpr int Y_OFF_H4  = Y_OFF / 8;               //  9,368
constexpr int Y_OFF_H8  = Y_OFF / 16;              //  4,684

// Color bases as COMPILE-TIME constants (validated R6/R8/R9/R10):
constexpr float FR[L_] = {  // mu = 620
    6.252150e-05f, 1.904358e-04f, 5.418690e-04f, 1.440515e-03f, 3.577400e-03f,
    8.299750e-03f, 1.798893e-02f, 3.642490e-02f, 6.890060e-02f, 1.217600e-01f,
    2.010120e-01f, 3.100190e-01f, 4.466857e-01f, 6.012587e-01f, 7.560710e-01f,
    8.881955e-01f, 9.747661e-01f, 9.993953e-01f, 9.572367e-01f, 8.565352e-01f,
    7.160078e-01f, 5.591580e-01f, 4.079402e-01f, 2.780373e-01f};
constexpr float FG[L_] = {  // mu = 550
    1.110900e-02f, 2.348440e-02f, 4.638000e-02f, 8.557090e-02f, 1.474900e-01f,
    2.374920e-01f, 3.572560e-01f, 5.020580e-01f, 6.591400e-01f, 8.084270e-01f,
    9.262975e-01f, 9.915296e-01f, 9.915296e-01f, 9.262975e-01f, 8.084270e-01f,
    6.591400e-01f, 5.020580e-01f, 3.572560e-01f, 2.374920e-01f, 1.474900e-01f,
    8.557090e-02f, 4.638000e-02f, 2.348440e-02f, 1.110900e-02f};
constexpr float FB[L_] = {  // mu = 450 (pairs with wb)
    6.065307e-01f, 7.609727e-01f, 8.919300e-01f, 9.766475e-01f, 9.990553e-01f,
    9.547420e-01f, 8.523698e-01f, 7.109096e-01f, 5.539184e-01f, 4.032022e-01f,
    2.741855e-01f, 1.741852e-01f, 1.033776e-01f, 5.731640e-02f, 2.968800e-02f,
    1.436580e-02f, 6.494090e-03f, 2.742560e-03f, 1.079230e-03f, 3.988070e-04f,
    1.369660e-04f, 4.417250e-05f, 1.327420e-05f, 3.726650e-06f};
constexpr float FC[L_] = {  // mu = 500 (pairs with wc)
    1.353353e-01f, 2.204053e-01f, 3.353338e-01f, 4.766271e-01f, 6.328849e-01f,
    7.850828e-01f, 9.098110e-01f, 9.849909e-01f, 9.962264e-01f, 9.413024e-01f,
    8.308921e-01f, 6.851808e-01f, 5.278508e-01f, 3.798934e-01f, 2.554222e-01f,
    1.604349e-01f, 9.414200e-02f, 5.160780e-02f, 2.642960e-02f, 1.264440e-02f,
    5.651680e-03f, 2.359870e-03f, 9.205430e-04f, 3.354630e-04f};

__device__ __forceinline__ float fdot2(h2 a, h2 b, float c) {
    return __builtin_amdgcn_fdot2(a, b, c, false);
}

// R22 (resubmitted — broker timed out before it ran): R21 killed the spill
// (VGPR 232, WRITE 26MB=output) and confirmed the allocator model (budget =
// 65536/wg_size). New bottleneck from counters: Occupancy 10.5% ~= 1
// block/CU (R19 measured 20% at the same 8-wave theoretical) -> the 2nd
// block never co-schedules. Mechanism: 232 VGPRs rounds to the 256 quantum;
// 8 waves x 256 = 2048 = the ENTIRE per-CU VGPR pool -> HW won't pack 2
// blocks. Fix: __launch_bounds__(256, 3) hard-caps VGPR at ~168 (8 x
// <=192-quantum <= 1536 <= 2048) -> both blocks resident -> 2 waves/SIMD
// latency hiding with the no-spill structure intact.
// Falsifier: WRITE >> 26MB means the cap re-introduced spill.
__global__ __launch_bounds__(256, 3)
void cassi_fused(
    const float* __restrict__ x,
    const float* __restrict__ wr, const float* __restrict__ wg,
    const float* __restrict__ wb, const float* __restrict__ wc,
    float* __restrict__ out, float* __restrict__ bmax_out)
{
    __shared__ __align__(16) char lds_raw[LDS_BYTES];
    h4* A4  = reinterpret_cast<h4*>(lds_raw);
    h2* XT2 = reinterpret_cast<h2*>(lds_raw) + XT_OFF_H2;
    h4* Y4  = reinterpret_cast<h4*>(lds_raw) + Y_OFF_H4;
    h8* Y8  = reinterpret_cast<h8*>(lds_raw) + Y_OFF_H8;
    float* wmax = reinterpret_cast<float*>(lds_raw + WMAX_OFF);

    const int t  = threadIdx.x;          // 0..255: column
    const int m  = blockIdx.x >> 1;      // row
    const int bp = blockIdx.x & 1;       // b-pair: handles b = 2bp, 2bp+1
    const int b0 = 2 * bp, b1 = 2 * bp + 1;

    // ---- Staging ----
    // zero A pad rows s=22,23 (514 h4): 256 threads x2 + 2 guarded.
    {
        h4 z; z.x = z.y = z.z = z.w = (_Float16)0.f;
        A4[S_ * AP_ + t] = z;
        A4[S_ * AP_ + 256 + t] = z;
        if (t < 2) A4[S_ * AP_ + 512 + t] = z;
    }
    // x: thread t stages column n=t for THIS block's two b -> XT2[n][l] h2.
    {
        const float4* xa = reinterpret_cast<const float4*>(x + ((b0 * M_ + m) * N_ + t) * L_);
        const float4* xb = reinterpret_cast<const float4*>(x + ((b1 * M_ + m) * N_ + t) * L_);
        #pragma unroll
        for (int i = 0; i < 6; ++i) {
            const float4 va = xa[i], vb = xb[i];
            h2 c0; c0.x=(_Float16)va.x; c0.y=(_Float16)vb.x;
            h2 c1; c1.x=(_Float16)va.y; c1.y=(_Float16)vb.y;
            h2 c2; c2.x=(_Float16)va.z; c2.y=(_Float16)vb.z;
            h2 c3; c3.x=(_Float16)va.w; c3.y=(_Float16)vb.w;
            XT2[t * XTP_ + 4 * i + 0] = c0;
            XT2[t * XTP_ + 4 * i + 1] = c1;
            XT2[t * XTP_ + 4 * i + 2] = c2;
            XT2[t * XTP_ + 4 * i + 3] = c3;
        }
    }
    // weights: coalesced, normalized once, h4-packed A[s][n] (both blocks of
    // a row stage this; second reader hits L2/L3).
    {
        const float* wrm = wr + m * (N_ * S_);
        const float* wgm = wg + m * (N_ * S_);
        const float* wbm = wb + m * (N_ * S_);
        const float* wcm = wc + m * (N_ * S_);
        #pragma unroll 1
        for (int i = 0; i < S_; ++i) {
            const int f = i * 256 + t;
            const float r = wrm[f], g = wgm[f], u = wbm[f], v = wcm[f];
            const int n = f / S_, s = f - n * S_;
            const float inv = 1.f / (r + g + u + v);
            h4 p;
            p.x = (_Float16)(r * inv); p.y = (_Float16)(g * inv);
            p.z = (_Float16)(u * inv); p.w = (_Float16)(v * inv);
            A4[s * AP_ + n] = p;
        }
    }
    __syncthreads();

    // ---- 6 alternating pass pairs: A(sq) fills Y, B(sq) consumes it.
    // X accumulators live across all passes (48 regs).
    float X0[L_], X1[L_];
    #pragma unroll
    for (int l = 0; l < L_; ++l) { X0[l] = 0.f; X1[l] = 0.f; }
    float vmax = 0.f;

    #pragma unroll 1
    for (int sq = 0; sq < 6; ++sq) {
        // ---- A-pass: Y[n'] gather for this sq. Wave 0 (t<64) dual
        // main+tail; waves 1-3 lean (idx = t-l >= 41). Wave-uniform branch.
        if (t < 64) {
            float4 aM0, aM1, aT0, aT1;
            aM0.x=aM0.y=aM0.z=aM0.w=0.f; aM1=aM0; aT0=aM0; aT1=aM0;
            #pragma unroll
            for (int l = 0; l < L_; ++l) {
                h2 f01; f01.x = (_Float16)FR[l]; f01.y = (_Float16)FG[l];
                h2 f23; f23.x = (_Float16)FB[l]; f23.y = (_Float16)FC[l];
                const bool mn = (l <= t);
                const int idx = mn ? (t - l) : (256 + t - l);
                const float mm = mn ? 1.f : 0.f;
                const int ab = (4 * sq) * AP_ + idx;
                const h4 p0 = A4[ab], p1 = A4[ab + AP_], p2 = A4[ab + 2 * AP_], p3 = A4[ab + 3 * AP_];
                const h2 xq = XT2[idx * XTP_ + l];
                const float g0 = fdot2(h2{p0.x,p0.y}, f01, fdot2(h2{p0.z,p0.w}, f23, 0.f));
                const float g1 = fdot2(h2{p1.x,p1.y}, f01, fdot2(h2{p1.z,p1.w}, f23, 0.f));
                const float g2 = fdot2(h2{p2.x,p2.y}, f01, fdot2(h2{p2.z,p2.w}, f23, 0.f));
                const float g3 = fdot2(h2{p3.x,p3.y}, f01, fdot2(h2{p3.z,p3.w}, f23, 0.f));
                const float gm0 = g0 * mm, gt0 = g0 - gm0;
                const float gm1 = g1 * mm, gt1 = g1 - gm1;
                const float gm2 = g2 * mm, gt2 = g2 - gm2;
                const float gm3 = g3 * mm, gt3 = g3 - gm3;
                const float xv0 = (float)xq.x, xv1 = (float)xq.y;
                aM0.x += gm0 * xv0; aT0.x += gt0 * xv0;
                aM0.y += gm1 * xv0; aT0.y += gt1 * xv0;
                aM0.z += gm2 * xv0; aT0.z += gt2 * xv0;
                aM0.w += gm3 * xv0; aT0.w += gt3 * xv0;
                aM1.x += gm0 * xv1; aT1.x += gt0 * xv1;
                aM1.y += gm1 * xv1; aT1.y += gt1 * xv1;
                aM1.z += gm2 * xv1; aT1.z += gt2 * xv1;
                aM1.w += gm3 * xv1; aT1.w += gt3 * xv1;
            }
            h4 pm0, pm1;
            pm0.x=(_Float16)aM0.x; pm0.y=(_Float16)aM0.y; pm0.z=(_Float16)aM0.z; pm0.w=(_Float16)aM0.w;
            pm1.x=(_Float16)aM1.x; pm1.y=(_Float16)aM1.y; pm1.z=(_Float16)aM1.z; pm1.w=(_Float16)aM1.w;
            Y4[t * 2 + 0] = pm0;
            Y4[t * 2 + 1] = pm1;
            if (t < 23) {
                h4 pt0, pt1;
                pt0.x=(_Float16)aT0.x; pt0.y=(_Float16)aT0.y; pt0.z=(_Float16)aT0.z; pt0.w=(_Float16)aT0.w;
                pt1.x=(_Float16)aT1.x; pt1.y=(_Float16)aT1.y; pt1.z=(_Float16)aT1.z; pt1.w=(_Float16)aT1.w;
                Y4[(256 + t) * 2 + 0] = pt0;
                Y4[(256 + t) * 2 + 1] = pt1;
            }
        } else {
            float4 aM0, aM1;
            aM0.x=aM0.y=aM0.z=aM0.w=0.f; aM1=aM0;
            #pragma unroll
            for (int l = 0; l < L_; ++l) {
                h2 f01; f01.x = (_Float16)FR[l]; f01.y = (_Float16)FG[l];
                h2 f23; f23.x = (_Float16)FB[l]; f23.y = (_Float16)FC[l];
                const int idx = t - l;      // t >= 64 -> always >= 41
                const int ab = (4 * sq) * AP_ + idx;
                const h4 p0 = A4[ab], p1 = A4[ab + AP_], p2 = A4[ab + 2 * AP_], p3 = A4[ab + 3 * AP_];
                const h2 xq = XT2[idx * XTP_ + l];
                const float g0 = fdot2(h2{p0.x,p0.y}, f01, fdot2(h2{p0.z,p0.w}, f23, 0.f));
                const float g1 = fdot2(h2{p1.x,p1.y}, f01, fdot2(h2{p1.z,p1.w}, f23, 0.f));
                const float g2 = fdot2(h2{p2.x,p2.y}, f01, fdot2(h2{p2.z,p2.w}, f23, 0.f));
                const float g3 = fdot2(h2{p3.x,p3.y}, f01, fdot2(h2{p3.z,p3.w}, f23, 0.f));
                const float xv0 = (float)xq.x, xv1 = (float)xq.y;
                aM0.x += g0 * xv0; aM1.x += g0 * xv1;
                aM0.y += g1 * xv0; aM1.y += g1 * xv1;
                aM0.z += g2 * xv0; aM1.z += g2 * xv1;
                aM0.w += g3 * xv0; aM1.w += g3 * xv1;
            }
            h4 pm0, pm1;
            pm0.x=(_Float16)aM0.x; pm0.y=(_Float16)aM0.y; pm0.z=(_Float16)aM0.z; pm0.w=(_Float16)aM0.w;
            pm1.x=(_Float16)aM1.x; pm1.y=(_Float16)aM1.y; pm1.z=(_Float16)aM1.z; pm1.w=(_Float16)aM1.w;
            Y4[t * 2 + 0] = pm0;
            Y4[t * 2 + 1] = pm1;
        }
        __syncthreads();

        // ---- B-pass: X[b][t][l] += sum over this sq's 4 shots.
        {
            const int ab = (4 * sq) * AP_ + t;
            const h4 q0 = A4[ab], q1 = A4[ab + AP_], q2 = A4[ab + 2 * AP_], q3 = A4[ab + 3 * AP_];
            #pragma unroll
            for (int l = 0; l < L_; ++l) {
                h2 f01; f01.x = (_Float16)FR[l]; f01.y = (_Float16)FG[l];
                h2 f23; f23.x = (_Float16)FB[l]; f23.y = (_Float16)FC[l];
                const float g0 = fdot2(h2{q0.x,q0.y}, f01, fdot2(h2{q0.z,q0.w}, f23, 0.f));
                const float g1 = fdot2(h2{q1.x,q1.y}, f01, fdot2(h2{q1.z,q1.w}, f23, 0.f));
                const float g2 = fdot2(h2{q2.x,q2.y}, f01, fdot2(h2{q2.z,q2.w}, f23, 0.f));
                const float g3 = fdot2(h2{q3.x,q3.y}, f01, fdot2(h2{q3.z,q3.w}, f23, 0.f));
                h2 G01; G01.x = (_Float16)g0; G01.y = (_Float16)g1;
                h2 G23; G23.x = (_Float16)g2; G23.y = (_Float16)g3;
                const h8 y = Y8[t + l];
                X0[l] = fdot2(G01, h2{y[0],y[1]}, fdot2(G23, h2{y[2],y[3]}, X0[l]));
                X1[l] = fdot2(G01, h2{y[4],y[5]}, fdot2(G23, h2{y[6],y[7]}, X1[l]));
            }
        }
        __syncthreads();   // Y buffer free for next sq
    }

    // ---- Output: contiguous 96B burst per (b, row t) + running max.
    {
        float4* o0 = reinterpret_cast<float4*>(out + ((b0 * M_ + m) * N_ + t) * L_);
        float4* o1 = reinterpret_cast<float4*>(out + ((b1 * M_ + m) * N_ + t) * L_);
        #pragma unroll
        for (int i = 0; i < 6; ++i) {
            float4 v0, v1;
            v0.x = X0[4*i+0]; v0.y = X0[4*i+1]; v0.z = X0[4*i+2]; v0.w = X0[4*i+3];
            v1.x = X1[4*i+0]; v1.y = X1[4*i+1]; v1.z = X1[4*i+2]; v1.w = X1[4*i+3];
            vmax = fmaxf(vmax, fmaxf(fmaxf(v0.x, v0.y), fmaxf(v0.z, v0.w)));
            vmax = fmaxf(vmax, fmaxf(fmaxf(v1.x, v1.y), fmaxf(v1.z, v1.w)));
            o0[i] = v0;
            o1[i] = v1;
        }
    }

    #pragma unroll
    for (int off = 32; off > 0; off >>= 1)
        vmax = fmaxf(vmax, __shfl_xor(vmax, off, 64));
    if ((t & 63) == 0) wmax[t >> 6] = vmax;
    __syncthreads();
    if (t == 0)
        bmax_out[blockIdx.x] = fmaxf(fmaxf(wmax[0], wmax[1]), fmaxf(wmax[2], wmax[3]));
}

// Normalize; each block re-reduces the 512 per-block maxes itself.
__global__ __launch_bounds__(256) void cassi_norm(float* __restrict__ out,
                                                  const float* __restrict__ bmax)
{
    __shared__ float wm[4];
    const int t = threadIdx.x;
    float v = fmaxf(bmax[t], bmax[t + 256]);
    #pragma unroll
    for (int off = 32; off > 0; off >>= 1)
        v = fmaxf(v, __shfl_xor(v, off, 64));
    if ((t & 63) == 0) wm[t >> 6] = v;
    __syncthreads();
    const float inv = 1.f / fmaxf(fmaxf(wm[0], wm[1]), fmaxf(wm[2], wm[3]));
    const int i = (blockIdx.x * 256 + t) * 4;
    float4 q = *reinterpret_cast<float4*>(out + i);
    q.x *= inv; q.y *= inv; q.z *= inv; q.w *= inv;
    *reinterpret_cast<float4*>(out + i) = q;
}

extern "C" void kernel_launch(void* const* d_in, const int* in_sizes, int n_in,
                              void* d_out, int out_size, void* d_ws, size_t ws_size,
                              hipStream_t stream) {
    const float* x  = (const float*)d_in[0];
    const float* wr = (const float*)d_in[1];
    const float* wg = (const float*)d_in[2];
    const float* wb = (const float*)d_in[3];
    const float* wc = (const float*)d_in[4];
    float* out  = (float*)d_out;
    float* bmax = (float*)d_ws;          // 512 per-block maxes (2KB)

    cassi_fused<<<2 * M_, 256, 0, stream>>>(x, wr, wg, wb, wc, out, bmax);
    const int n4blocks = (B_ * M_ * N_ * L_) / 4 / 256;     // 6144, exact
    cassi_norm<<<n4blocks, 256, 0, stream>>>(out, bmax);
}